// Round 1
// baseline (1129.054 us; speedup 1.0000x reference)
//
#include <hip/hip_runtime.h>
#include <stdint.h>

// LlamaGQA on MI355X (gfx950).
// Pipeline: cvt(fp32->bf16) x,wq,wk,wv -> gemm Q,K,V (MFMA bf16, B^T layout)
//           -> flash attention (MFMA, online softmax) -> cvt wo -> gemm O (fp32 out).
// V is written pre-transposed [b,hk,d,s] by the V-proj epilogue so PV's B-frag
// is a contiguous ds_read_b128. K/V LDS tiles XOR-swizzled (G4) via
// pre-swizzled global_load_lds source addresses (m173 pattern).
// Workspace layout (bf16 elems): x(16.8M) wbig(16.8M, wq then wo) wk(4.2M)
// wv(4.2M) Q(16.8M) K(4.2M) Vt(4.2M) AO(16.8M) = 167.8 MB total.

typedef __attribute__((ext_vector_type(4))) float f32x4;
typedef __attribute__((ext_vector_type(4))) float float4v;
typedef __attribute__((ext_vector_type(8))) short short8;
typedef __attribute__((ext_vector_type(8))) __bf16 bf16x8;
typedef __attribute__((ext_vector_type(4))) unsigned short ushort4v;

#define B_SZ 2
#define S_SZ 2048
#define DIM_SZ 4096
#define NH 32
#define NKV 8
#define HD 128
// softmax scale folded into exp2: 1/sqrt(128) * log2(e)
#define CEXP 0.12752531f

static __device__ __forceinline__ unsigned short f2bf(float f) {
  unsigned int u = __builtin_bit_cast(unsigned int, f);
  u = (u + 0x7fffu + ((u >> 16) & 1u)) >> 16;  // RNE
  return (unsigned short)u;
}
static __device__ __forceinline__ float bf2f(unsigned short h) {
  unsigned int u = ((unsigned int)h) << 16;
  return __builtin_bit_cast(float, u);
}
static __device__ __forceinline__ f32x4 mfma16(short8 a, short8 b, f32x4 c) {
  return __builtin_amdgcn_mfma_f32_16x16x32_bf16(
      __builtin_bit_cast(bf16x8, a), __builtin_bit_cast(bf16x8, b), c, 0, 0, 0);
}
static __device__ __forceinline__ void gload16(const void* g, void* l) {
  __builtin_amdgcn_global_load_lds(
      (const __attribute__((address_space(1))) unsigned int*)g,
      (__attribute__((address_space(3))) unsigned int*)l, 16, 0, 0);
}

// ---------------- fp32 -> bf16 conversion (memory-bound, float4/thread) -----
__global__ __launch_bounds__(256) void cvt_kernel(const float* __restrict__ src,
                                                  unsigned short* __restrict__ dst,
                                                  int n4) {
  int i = blockIdx.x * 256 + threadIdx.x;
  if (i >= n4) return;
  float4v v = ((const float4v*)src)[i];
  ushort4v o;
  o[0] = f2bf(v[0]); o[1] = f2bf(v[1]); o[2] = f2bf(v[2]); o[3] = f2bf(v[3]);
  ((ushort4v*)dst)[i] = o;
}

// ---------------- bf16 GEMM, C[m][n] = sum_k A[m][k]*B[n][k] ----------------
// m97 structure: 128x128 tile, BK=32, 4 waves (each 64x64 = 4x4 16x16 frags),
// global_load_lds width 16, 2 barriers per K-step. LDS slot-XOR swizzle (x4).
// EPI 0: fp32 row-major [M][N] (final output)
// EPI 1: bf16 [b, h, s, d]   (Q, K;  n = h*128+d, m = b*2048+s)
// EPI 2: bf16 [b, h, d, s]   (V transposed; packed short4 store along s)
template <int EPI>
__global__ __launch_bounds__(256) void gemm_bt(const unsigned short* __restrict__ A,
                                               const unsigned short* __restrict__ B,
                                               void* __restrict__ Cout,
                                               int N, int K, int H) {
  __shared__ unsigned short As[128 * 32];
  __shared__ unsigned short Bs[128 * 32];
  const int tid = threadIdx.x;
  const int lane = tid & 63;
  const int wave = tid >> 6;
  const int wr = wave >> 1, wc = wave & 1;
  const int m0 = blockIdx.y * 128, n0 = blockIdx.x * 128;

  f32x4 acc[4][4] = {};

  // staging: row = call*64 + tid/4, phys 16B-slot = tid&3.
  // pre-swizzle the global source: logical chunk = slot ^ (row&3).
  const int srow = tid >> 2;
  const int swz8 = ((tid & 3) ^ (srow & 3)) * 8;
  const unsigned short* Ap0 = A + (size_t)(m0 + srow) * K + swz8;
  const unsigned short* Ap1 = Ap0 + (size_t)64 * K;
  const unsigned short* Bp0 = B + (size_t)(n0 + srow) * K + swz8;
  const unsigned short* Bp1 = Bp0 + (size_t)64 * K;
  unsigned short* Ad0 = As + tid * 8;
  unsigned short* Ad1 = As + 2048 + tid * 8;
  unsigned short* Bd0 = Bs + tid * 8;
  unsigned short* Bd1 = Bs + 2048 + tid * 8;

  const int fr = lane & 15;            // frag row (m or n within 16)
  const int fg = lane >> 4;            // frag k-group
  const int rsl = (fg ^ (fr & 3)) * 8; // swizzled read slot offset (elems)

#pragma unroll 1
  for (int kt = 0; kt < K; kt += 32) {
    gload16(Ap0 + kt, Ad0);
    gload16(Ap1 + kt, Ad1);
    gload16(Bp0 + kt, Bd0);
    gload16(Bp1 + kt, Bd1);
    __syncthreads();
    short8 a[4], b[4];
#pragma unroll
    for (int i = 0; i < 4; i++)
      a[i] = *(const short8*)&As[(wr * 64 + i * 16 + fr) * 32 + rsl];
#pragma unroll
    for (int i = 0; i < 4; i++)
      b[i] = *(const short8*)&Bs[(wc * 64 + i * 16 + fr) * 32 + rsl];
#pragma unroll
    for (int mi = 0; mi < 4; mi++)
#pragma unroll
      for (int ni = 0; ni < 4; ni++)
        acc[mi][ni] = mfma16(a[mi], b[ni], acc[mi][ni]);
    __syncthreads();
  }

  // epilogue: C/D layout col = lane&15 (n), row = (lane>>4)*4 + r (m)
#pragma unroll
  for (int mi = 0; mi < 4; mi++) {
#pragma unroll
    for (int ni = 0; ni < 4; ni++) {
      const int mb = m0 + wr * 64 + mi * 16 + fg * 4;
      const int n = n0 + wc * 64 + ni * 16 + fr;
      if (EPI == 0) {
        float* C = (float*)Cout;
#pragma unroll
        for (int r = 0; r < 4; r++) C[(size_t)(mb + r) * N + n] = acc[mi][ni][r];
      } else if (EPI == 1) {
        unsigned short* C = (unsigned short*)Cout;
        const int h = n >> 7, d = n & 127;
#pragma unroll
        for (int r = 0; r < 4; r++) {
          const int m = mb + r;
          const int bb = m >> 11, s = m & 2047;
          C[(((size_t)(bb * H + h)) * S_SZ + s) * HD + d] = f2bf(acc[mi][ni][r]);
        }
      } else {
        unsigned short* C = (unsigned short*)Cout;
        const int h = n >> 7, d = n & 127;
        const int bb = mb >> 11, s = mb & 2047;  // 4 consecutive s per lane
        ushort4v pk;
#pragma unroll
        for (int r = 0; r < 4; r++) pk[r] = f2bf(acc[mi][ni][r]);
        *(ushort4v*)&C[(((size_t)(bb * NKV + h)) * HD + d) * S_SZ + s] = pk;
      }
    }
  }
}

// ---------------- flash attention (no mask), bf16 MFMA ----------------------
// Block: 64 q-rows of one (b,h); 4 waves x 16 q-rows. Loop KV tiles of 64.
// Q in regs (A-frags). K LDS [64][128] and Vt LDS [128][64], both slot-XOR
// swizzled (slot ^= row&7) via pre-swizzled global_load_lds sources.
// S frags: row=q, col=key. Row softmax via 16-lane shfl_xor butterfly.
// P staged per-wave in LDS [16][72] (pad 8), re-read as PV A-frags.
__global__ __launch_bounds__(256) void attn_kernel(const unsigned short* __restrict__ Q,
                                                   const unsigned short* __restrict__ Kg,
                                                   const unsigned short* __restrict__ Vt,
                                                   unsigned short* __restrict__ AO) {
  __shared__ unsigned short Ks[64 * 128];
  __shared__ unsigned short Vs[128 * 64];
  __shared__ unsigned short Ps[4][16 * 72];
  const int tid = threadIdx.x, lane = tid & 63, wave = tid >> 6;
  const int qt = blockIdx.x, h = blockIdx.y, b = blockIdx.z;
  const int hk = h >> 2;  // groups = 4
  const size_t qbase = ((size_t)(b * NH + h) * S_SZ) * HD;
  const size_t kbase = ((size_t)(b * NKV + hk) * S_SZ) * HD;
  const size_t vbase = ((size_t)(b * NKV + hk) * HD) * S_SZ;
  const int q0 = qt * 64 + wave * 16;
  const int fr = lane & 15, fg = lane >> 4;

  short8 qf[4];
#pragma unroll
  for (int dc = 0; dc < 4; dc++)
    qf[dc] = *(const short8*)&Q[qbase + (size_t)(q0 + fr) * HD + dc * 32 + fg * 8];

  f32x4 acco[8] = {};
  float m_r[4], l_r[4];
#pragma unroll
  for (int r = 0; r < 4; r++) { m_r[r] = -3.0e38f; l_r[r] = 0.f; }

  const int krow = tid >> 4, kslot = tid & 15;
  const int vrow = tid >> 3, vslot = tid & 7;

#pragma unroll 1
  for (int kt = 0; kt < S_SZ; kt += 64) {
    // stage K tile [64][128]: 4 call-sites x 4KB
#pragma unroll
    for (int i = 0; i < 4; i++) {
      const int row = i * 16 + krow;
      const int c = kslot ^ (row & 7);
      gload16(&Kg[kbase + (size_t)(kt + row) * HD + c * 8], &Ks[i * 2048 + tid * 8]);
    }
    // stage Vt tile [128][64]: 4 call-sites x 4KB
#pragma unroll
    for (int i = 0; i < 4; i++) {
      const int row = i * 32 + vrow;
      const int c = vslot ^ (row & 7);
      gload16(&Vt[vbase + (size_t)row * S_SZ + kt + c * 8], &Vs[i * 2048 + tid * 8]);
    }
    __syncthreads();

    // S = Q K^T  (raw logits; scale folded into CEXP)
    f32x4 sf[4] = {};
#pragma unroll
    for (int kb = 0; kb < 4; kb++) {
      const int row = kb * 16 + fr;
#pragma unroll
      for (int dc = 0; dc < 4; dc++) {
        const int slot = (dc * 4 + fg) ^ (row & 7);
        short8 kf = *(const short8*)&Ks[row * 128 + slot * 8];
        sf[kb] = mfma16(qf[dc], kf, sf[kb]);
      }
    }

    // online softmax; write P (bf16) to per-wave LDS
#pragma unroll
    for (int r = 0; r < 4; r++) {
      float tmax = fmaxf(fmaxf(sf[0][r], sf[1][r]), fmaxf(sf[2][r], sf[3][r]));
      tmax = fmaxf(tmax, __shfl_xor(tmax, 1));
      tmax = fmaxf(tmax, __shfl_xor(tmax, 2));
      tmax = fmaxf(tmax, __shfl_xor(tmax, 4));
      tmax = fmaxf(tmax, __shfl_xor(tmax, 8));
      const float mnew = fmaxf(m_r[r], tmax);
      const float alpha = __builtin_amdgcn_exp2f((m_r[r] - mnew) * CEXP);
      m_r[r] = mnew;
      float ps = 0.f;
      const int prow = fg * 4 + r;
#pragma unroll
      for (int kb = 0; kb < 4; kb++) {
        const unsigned short pb = f2bf(__builtin_amdgcn_exp2f((sf[kb][r] - mnew) * CEXP));
        ps += bf2f(pb);  // sum the rounded value PV will actually use
        Ps[wave][prow * 72 + kb * 16 + fr] = pb;
      }
      ps += __shfl_xor(ps, 1);
      ps += __shfl_xor(ps, 2);
      ps += __shfl_xor(ps, 4);
      ps += __shfl_xor(ps, 8);
      l_r[r] = l_r[r] * alpha + ps;
#pragma unroll
      for (int dt = 0; dt < 8; dt++) acco[dt][r] *= alpha;
    }

    // O += P V   (A = P from LDS, B = Vt rows, contiguous along key)
    short8 pf[2];
#pragma unroll
    for (int kc = 0; kc < 2; kc++)
      pf[kc] = *(const short8*)&Ps[wave][fr * 72 + kc * 32 + fg * 8];
#pragma unroll
    for (int dt = 0; dt < 8; dt++) {
      const int row = dt * 16 + fr;
#pragma unroll
      for (int kc = 0; kc < 2; kc++) {
        const int slot = (kc * 4 + fg) ^ (row & 7);
        short8 vf = *(const short8*)&Vs[row * 64 + slot * 8];
        acco[dt] = mfma16(pf[kc], vf, acco[dt]);
      }
    }
    __syncthreads();
  }

  // epilogue: AO[b][s][h][d] bf16
#pragma unroll
  for (int r = 0; r < 4; r++) {
    const float inv = 1.0f / l_r[r];
    const int s = q0 + fg * 4 + r;
    const size_t ob = (((size_t)(b * S_SZ + s)) * NH + h) * HD;
#pragma unroll
    for (int dt = 0; dt < 8; dt++)
      AO[ob + dt * 16 + fr] = f2bf(acco[dt][r] * inv);
  }
}

// ----------------------------------------------------------------------------
extern "C" void kernel_launch(void* const* d_in, const int* in_sizes, int n_in,
                              void* d_out, int out_size, void* d_ws, size_t ws_size,
                              hipStream_t stream) {
  const float* x  = (const float*)d_in[0];
  const float* wq = (const float*)d_in[1];
  const float* wk = (const float*)d_in[2];
  const float* wv = (const float*)d_in[3];
  const float* wo = (const float*)d_in[4];

  unsigned short* ws = (unsigned short*)d_ws;
  const size_t SZ_BIG = (size_t)DIM_SZ * DIM_SZ;        // 16.78M elems
  const size_t SZ_SMALL = (size_t)(NKV * HD) * DIM_SZ;  // 4.19M elems
  unsigned short* xb   = ws;                 // x bf16 [4096][4096] (m=(b,s), k)
  unsigned short* wbig = xb + SZ_BIG;        // wq, later wo
  unsigned short* wkb  = wbig + SZ_BIG;
  unsigned short* wvb  = wkb + SZ_SMALL;
  unsigned short* Qb   = wvb + SZ_SMALL;     // [b,h,s,d]
  unsigned short* Kb   = Qb + SZ_BIG;        // [b,hk,s,d]
  unsigned short* Vtb  = Kb + SZ_SMALL;      // [b,hk,d,s]
  unsigned short* AOb  = Vtb + SZ_SMALL;     // [b,s,h,d]

  // fp32 -> bf16
  cvt_kernel<<<16384, 256, 0, stream>>>(x, xb, 4194304);
  cvt_kernel<<<16384, 256, 0, stream>>>(wq, wbig, 4194304);
  cvt_kernel<<<4096, 256, 0, stream>>>(wk, wkb, 1048576);
  cvt_kernel<<<4096, 256, 0, stream>>>(wv, wvb, 1048576);

  // projections (M = 4096 = B*S, K = 4096)
  gemm_bt<1><<<dim3(32, 32), 256, 0, stream>>>(xb, wbig, Qb, 4096, DIM_SZ, NH);
  gemm_bt<1><<<dim3(8, 32), 256, 0, stream>>>(xb, wkb, Kb, 1024, DIM_SZ, NKV);
  gemm_bt<2><<<dim3(8, 32), 256, 0, stream>>>(xb, wvb, Vtb, 1024, DIM_SZ, NKV);

  // attention: grid (qtiles=32, heads=32, batch=2)
  attn_kernel<<<dim3(32, 32, 2), 256, 0, stream>>>(Qb, Kb, Vtb, AOb);

  // output projection (fp32 out)
  cvt_kernel<<<16384, 256, 0, stream>>>(wo, wbig, 4194304);
  gemm_bt<0><<<dim3(32, 32), 256, 0, stream>>>(AOb, wbig, d_out, 4096, DIM_SZ, NH);
}

// Round 2
// 869.553 us; speedup vs baseline: 1.2984x; 1.2984x over previous
//
#include <hip/hip_runtime.h>
#include <stdint.h>

// LlamaGQA on MI355X (gfx950).
// r2: Q/O projections moved to the 256^2 8-phase template (BK=64, 8 waves,
// 128KB LDS double-buffer, chunk-XOR swizzle both-sides, counted vmcnt(4),
// setprio around MFMA clusters). K+V merged into one N=2048 128^2 GEMM
// (EPI3 routes n<1024 -> K [b,hk,s,d], n>=1024 -> V^T [b,hk,d,s]).
// Attention unchanged from r1 (rewrite scheduled next round).

typedef __attribute__((ext_vector_type(4))) float f32x4;
typedef __attribute__((ext_vector_type(4))) float float4v;
typedef __attribute__((ext_vector_type(8))) short short8;
typedef __attribute__((ext_vector_type(8))) __bf16 bf16x8;
typedef __attribute__((ext_vector_type(4))) unsigned short ushort4v;

#define B_SZ 2
#define S_SZ 2048
#define DIM_SZ 4096
#define NH 32
#define NKV 8
#define HD 128
#define CEXP 0.12752531f  // 1/sqrt(128) * log2(e)

static __device__ __forceinline__ unsigned short f2bf(float f) {
  unsigned int u = __builtin_bit_cast(unsigned int, f);
  u = (u + 0x7fffu + ((u >> 16) & 1u)) >> 16;  // RNE
  return (unsigned short)u;
}
static __device__ __forceinline__ float bf2f(unsigned short h) {
  unsigned int u = ((unsigned int)h) << 16;
  return __builtin_bit_cast(float, u);
}
static __device__ __forceinline__ f32x4 mfma16(short8 a, short8 b, f32x4 c) {
  return __builtin_amdgcn_mfma_f32_16x16x32_bf16(
      __builtin_bit_cast(bf16x8, a), __builtin_bit_cast(bf16x8, b), c, 0, 0, 0);
}
static __device__ __forceinline__ void gload16(const void* g, void* l) {
  __builtin_amdgcn_global_load_lds(
      (const __attribute__((address_space(1))) unsigned int*)g,
      (__attribute__((address_space(3))) unsigned int*)l, 16, 0, 0);
}

// ---------------- fp32 -> bf16 conversion ----------------------------------
__global__ __launch_bounds__(256) void cvt_kernel(const float* __restrict__ src,
                                                  unsigned short* __restrict__ dst,
                                                  int n4) {
  int i = blockIdx.x * 256 + threadIdx.x;
  if (i >= n4) return;
  float4v v = ((const float4v*)src)[i];
  ushort4v o;
  o[0] = f2bf(v[0]); o[1] = f2bf(v[1]); o[2] = f2bf(v[2]); o[3] = f2bf(v[3]);
  ((ushort4v*)dst)[i] = o;
}

// ---------------- 256x256 8-phase bf16 GEMM (C = A * B^T) -------------------
// BM=BN=256, BK=64, 512 threads = 8 waves (2M x 4N), per-wave C = 128x64.
// LDS 128KB: [buf2][A/B][half2][128 rows][64 cols] bf16, chunk-XOR swizzled
// (chunk ^= row&7) via pre-swizzled global source + swizzled ds_read.
// Per K-tile: 4 phases {dsread(12/4/8/0) | stage 1 half-tile | bar | lgkm0 |
// 16 MFMA} ; vmcnt(4) once per tile (phase 4). Stage schedule:
// P1:A0(t+1) P2:A1(t+1) P3:B0(t+2) P4:B1(t+2).
// EPI 0: fp32 [M][N].  EPI 1: bf16 [b,h,s,d].
template <int EPI>
__global__ __launch_bounds__(512, 2) void gemm256(const unsigned short* __restrict__ A,
                                                  const unsigned short* __restrict__ B,
                                                  void* __restrict__ Cout,
                                                  int N, int K, int H) {
  __shared__ unsigned short lds[65536];  // 128 KiB
  const int tid = threadIdx.x;
  const int lane = tid & 63;
  const int wave = tid >> 6;   // 0..7
  const int wm = wave >> 2;    // 0..1  (M half)
  const int wn = wave & 3;     // 0..3  (N quarter)
  const int fr = lane & 15, fg = lane >> 4;
  const int m0 = blockIdx.y * 256, n0 = blockIdx.x * 256;
  const int NT = K >> 6;

  // LDS segment: [buf][ab][half] * 8192 ushorts (16KB)
  auto seg = [&](int buf, int ab, int half) -> unsigned short* {
    return lds + ((((buf << 1) | ab) << 1) | half) * 8192;
  };

  // staging: thread t covers LDS chunks t and t+512 of a 128x64 half-tile.
  // LDS chunk p -> (row=p>>3, c=p&7); source global chunk col = c ^ (row&7).
  const int srow = tid >> 3;                        // 0..63
  const int scol = ((tid & 7) ^ (srow & 7)) << 3;   // elems
  const unsigned short* Abase = A + (size_t)(m0 + srow) * K + scol;
  const unsigned short* Bbase = B + (size_t)(n0 + srow) * K + scol;

  auto stageA = [&](int t, int h) {
    const unsigned short* g = Abase + (size_t)(h * 128) * K + t * 64;
    unsigned short* d = seg(t & 1, 0, h);
    gload16(g, d + tid * 8);
    gload16(g + (size_t)64 * K, d + 4096 + tid * 8);
  };
  auto stageB = [&](int t, int h) {
    const unsigned short* g = Bbase + (size_t)(h * 128) * K + t * 64;
    unsigned short* d = seg(t & 1, 1, h);
    gload16(g, d + tid * 8);
    gload16(g + (size_t)64 * K, d + 4096 + tid * 8);
  };

  f32x4 acc[8][4] = {};

  // prologue: A(0) x2, B(0) x2, B(1) x2 halves; A(1) comes in P1/P2 of t=0.
  stageA(0, 0); stageA(0, 1);
  stageB(0, 0); stageB(0, 1);
  stageB(1, 0); stageB(1, 1);
  asm volatile("s_waitcnt vmcnt(4)" ::: "memory");
  __builtin_amdgcn_s_barrier();

#pragma unroll 1
  for (int t = 0; t < NT; ++t) {
    const unsigned short* Aseg = seg(t & 1, 0, wm);
    const unsigned short* Bseg = seg(t & 1, 1, wn >> 1);
    const int brow0 = (wn & 1) * 64;
    short8 aR[4][2], b01[2][2], b23[2][2];

    // ---------------- phase 1: read a[0-3], b[0-1]; stage A0(t+1); Q0
#pragma unroll
    for (int mi = 0; mi < 4; ++mi)
#pragma unroll
      for (int ks = 0; ks < 2; ++ks) {
        const int row = mi * 16 + fr;
        aR[mi][ks] = *(const short8*)&Aseg[row * 64 + ((((ks << 2) + fg) ^ (row & 7)) << 3)];
      }
#pragma unroll
    for (int ni = 0; ni < 2; ++ni)
#pragma unroll
      for (int ks = 0; ks < 2; ++ks) {
        const int row = brow0 + ni * 16 + fr;
        b01[ni][ks] = *(const short8*)&Bseg[row * 64 + ((((ks << 2) + fg) ^ (row & 7)) << 3)];
      }
    if (t + 1 < NT) stageA(t + 1, 0);
    __builtin_amdgcn_sched_barrier(0);
    __builtin_amdgcn_s_barrier();
    asm volatile("s_waitcnt lgkmcnt(0)" ::: "memory");
    __builtin_amdgcn_sched_barrier(0);
    __builtin_amdgcn_s_setprio(1);
#pragma unroll
    for (int mi = 0; mi < 4; ++mi)
#pragma unroll
      for (int ni = 0; ni < 2; ++ni)
#pragma unroll
        for (int ks = 0; ks < 2; ++ks)
          acc[mi][ni] = mfma16(aR[mi][ks], b01[ni][ks], acc[mi][ni]);
    __builtin_amdgcn_s_setprio(0);
    __builtin_amdgcn_sched_barrier(0);
    __builtin_amdgcn_s_barrier();

    // ---------------- phase 2: read b[2-3]; stage A1(t+1); Q1
#pragma unroll
    for (int ni = 0; ni < 2; ++ni)
#pragma unroll
      for (int ks = 0; ks < 2; ++ks) {
        const int row = brow0 + (ni + 2) * 16 + fr;
        b23[ni][ks] = *(const short8*)&Bseg[row * 64 + ((((ks << 2) + fg) ^ (row & 7)) << 3)];
      }
    if (t + 1 < NT) stageA(t + 1, 1);
    __builtin_amdgcn_sched_barrier(0);
    __builtin_amdgcn_s_barrier();
    asm volatile("s_waitcnt lgkmcnt(0)" ::: "memory");
    __builtin_amdgcn_sched_barrier(0);
    __builtin_amdgcn_s_setprio(1);
#pragma unroll
    for (int mi = 0; mi < 4; ++mi)
#pragma unroll
      for (int ni = 0; ni < 2; ++ni)
#pragma unroll
        for (int ks = 0; ks < 2; ++ks)
          acc[mi][ni + 2] = mfma16(aR[mi][ks], b23[ni][ks], acc[mi][ni + 2]);
    __builtin_amdgcn_s_setprio(0);
    __builtin_amdgcn_sched_barrier(0);
    __builtin_amdgcn_s_barrier();

    // ---------------- phase 3: read a[4-7]; stage B0(t+2); Q2
#pragma unroll
    for (int mi = 0; mi < 4; ++mi)
#pragma unroll
      for (int ks = 0; ks < 2; ++ks) {
        const int row = (mi + 4) * 16 + fr;
        aR[mi][ks] = *(const short8*)&Aseg[row * 64 + ((((ks << 2) + fg) ^ (row & 7)) << 3)];
      }
    if (t + 2 < NT) stageB(t + 2, 0);
    __builtin_amdgcn_sched_barrier(0);
    __builtin_amdgcn_s_barrier();
    asm volatile("s_waitcnt lgkmcnt(0)" ::: "memory");
    __builtin_amdgcn_sched_barrier(0);
    __builtin_amdgcn_s_setprio(1);
#pragma unroll
    for (int mi = 0; mi < 4; ++mi)
#pragma unroll
      for (int ni = 0; ni < 2; ++ni)
#pragma unroll
        for (int ks = 0; ks < 2; ++ks)
          acc[mi + 4][ni] = mfma16(aR[mi][ks], b01[ni][ks], acc[mi + 4][ni]);
    __builtin_amdgcn_s_setprio(0);
    __builtin_amdgcn_sched_barrier(0);
    __builtin_amdgcn_s_barrier();

    // ---------------- phase 4: stage B1(t+2); vmcnt; Q3
    if (t + 2 < NT) {
      stageB(t + 2, 1);
      __builtin_amdgcn_sched_barrier(0);
      asm volatile("s_waitcnt vmcnt(4)" ::: "memory");
    } else {
      __builtin_amdgcn_sched_barrier(0);
      asm volatile("s_waitcnt vmcnt(0)" ::: "memory");
    }
    __builtin_amdgcn_s_barrier();
    __builtin_amdgcn_s_setprio(1);
#pragma unroll
    for (int mi = 0; mi < 4; ++mi)
#pragma unroll
      for (int ni = 0; ni < 2; ++ni)
#pragma unroll
        for (int ks = 0; ks < 2; ++ks)
          acc[mi + 4][ni + 2] = mfma16(aR[mi][ks], b23[ni][ks], acc[mi + 4][ni + 2]);
    __builtin_amdgcn_s_setprio(0);
    __builtin_amdgcn_sched_barrier(0);
    __builtin_amdgcn_s_barrier();
  }

  // epilogue: C/D frag layout col = fr (n), row = fg*4 + r (m)
#pragma unroll
  for (int mi = 0; mi < 8; ++mi) {
#pragma unroll
    for (int ni = 0; ni < 4; ++ni) {
      const int mb = m0 + wm * 128 + mi * 16 + fg * 4;
      const int n = n0 + wn * 64 + ni * 16 + fr;
      if (EPI == 0) {
        float* C = (float*)Cout;
#pragma unroll
        for (int r = 0; r < 4; ++r) C[(size_t)(mb + r) * N + n] = acc[mi][ni][r];
      } else {
        unsigned short* C = (unsigned short*)Cout;
        const int h = n >> 7, d = n & 127;
#pragma unroll
        for (int r = 0; r < 4; ++r) {
          const int m = mb + r;
          const int bb = m >> 11, s = m & 2047;
          C[(((size_t)(bb * H + h)) * S_SZ + s) * HD + d] = f2bf(acc[mi][ni][r]);
        }
      }
    }
  }
}

// ---------------- 128x128 bf16 GEMM (m97 structure), KV merged --------------
// EPI 3: N=2048; n<1024 -> K bf16 [b,hk,s,d] (Cout); n>=1024 -> V^T bf16
// [b,hk,d,s] (Cout2, packed ushort4 along s).
template <int EPI>
__global__ __launch_bounds__(256) void gemm_bt(const unsigned short* __restrict__ A,
                                               const unsigned short* __restrict__ B,
                                               void* __restrict__ Cout,
                                               void* __restrict__ Cout2,
                                               int N, int K, int H) {
  __shared__ unsigned short As[128 * 32];
  __shared__ unsigned short Bs[128 * 32];
  const int tid = threadIdx.x;
  const int lane = tid & 63;
  const int wave = tid >> 6;
  const int wr = wave >> 1, wc = wave & 1;
  const int m0 = blockIdx.y * 128, n0 = blockIdx.x * 128;

  f32x4 acc[4][4] = {};

  const int srow = tid >> 2;
  const int swz8 = ((tid & 3) ^ (srow & 3)) * 8;
  const unsigned short* Ap0 = A + (size_t)(m0 + srow) * K + swz8;
  const unsigned short* Ap1 = Ap0 + (size_t)64 * K;
  const unsigned short* Bp0 = B + (size_t)(n0 + srow) * K + swz8;
  const unsigned short* Bp1 = Bp0 + (size_t)64 * K;
  unsigned short* Ad0 = As + tid * 8;
  unsigned short* Ad1 = As + 2048 + tid * 8;
  unsigned short* Bd0 = Bs + tid * 8;
  unsigned short* Bd1 = Bs + 2048 + tid * 8;

  const int fr = lane & 15;
  const int fg = lane >> 4;
  const int rsl = (fg ^ (fr & 3)) * 8;

#pragma unroll 1
  for (int kt = 0; kt < K; kt += 32) {
    gload16(Ap0 + kt, Ad0);
    gload16(Ap1 + kt, Ad1);
    gload16(Bp0 + kt, Bd0);
    gload16(Bp1 + kt, Bd1);
    __syncthreads();
    short8 a[4], b[4];
#pragma unroll
    for (int i = 0; i < 4; i++)
      a[i] = *(const short8*)&As[(wr * 64 + i * 16 + fr) * 32 + rsl];
#pragma unroll
    for (int i = 0; i < 4; i++)
      b[i] = *(const short8*)&Bs[(wc * 64 + i * 16 + fr) * 32 + rsl];
#pragma unroll
    for (int mi = 0; mi < 4; mi++)
#pragma unroll
      for (int ni = 0; ni < 4; ni++)
        acc[mi][ni] = mfma16(a[mi], b[ni], acc[mi][ni]);
    __syncthreads();
  }

#pragma unroll
  for (int mi = 0; mi < 4; mi++) {
#pragma unroll
    for (int ni = 0; ni < 4; ni++) {
      const int mb = m0 + wr * 64 + mi * 16 + fg * 4;
      const int n = n0 + wc * 64 + ni * 16 + fr;
      if (EPI == 0) {
        float* C = (float*)Cout;
#pragma unroll
        for (int r = 0; r < 4; r++) C[(size_t)(mb + r) * N + n] = acc[mi][ni][r];
      } else if (EPI == 1) {
        unsigned short* C = (unsigned short*)Cout;
        const int h = n >> 7, d = n & 127;
#pragma unroll
        for (int r = 0; r < 4; r++) {
          const int m = mb + r;
          const int bb = m >> 11, s = m & 2047;
          C[(((size_t)(bb * H + h)) * S_SZ + s) * HD + d] = f2bf(acc[mi][ni][r]);
        }
      } else if (EPI == 3) {
        if (n < 1024) {  // K: [b,hk,s,d]
          unsigned short* C = (unsigned short*)Cout;
          const int h = n >> 7, d = n & 127;
#pragma unroll
          for (int r = 0; r < 4; r++) {
            const int m = mb + r;
            const int bb = m >> 11, s = m & 2047;
            C[(((size_t)(bb * NKV + h)) * S_SZ + s) * HD + d] = f2bf(acc[mi][ni][r]);
          }
        } else {  // V^T: [b,hk,d,s], packed along s
          unsigned short* C = (unsigned short*)Cout2;
          const int vr = n - 1024;
          const int h = vr >> 7, d = vr & 127;
          const int bb = mb >> 11, s = mb & 2047;
          ushort4v pk;
#pragma unroll
          for (int r = 0; r < 4; r++) pk[r] = f2bf(acc[mi][ni][r]);
          *(ushort4v*)&C[(((size_t)(bb * NKV + h)) * HD + d) * S_SZ + s] = pk;
        }
      }
    }
  }
}

// ---------------- flash attention (unchanged from r1) -----------------------
__global__ __launch_bounds__(256) void attn_kernel(const unsigned short* __restrict__ Q,
                                                   const unsigned short* __restrict__ Kg,
                                                   const unsigned short* __restrict__ Vt,
                                                   unsigned short* __restrict__ AO) {
  __shared__ unsigned short Ks[64 * 128];
  __shared__ unsigned short Vs[128 * 64];
  __shared__ unsigned short Ps[4][16 * 72];
  const int tid = threadIdx.x, lane = tid & 63, wave = tid >> 6;
  const int qt = blockIdx.x, h = blockIdx.y, b = blockIdx.z;
  const int hk = h >> 2;
  const size_t qbase = ((size_t)(b * NH + h) * S_SZ) * HD;
  const size_t kbase = ((size_t)(b * NKV + hk) * S_SZ) * HD;
  const size_t vbase = ((size_t)(b * NKV + hk) * HD) * S_SZ;
  const int q0 = qt * 64 + wave * 16;
  const int fr = lane & 15, fg = lane >> 4;

  short8 qf[4];
#pragma unroll
  for (int dc = 0; dc < 4; dc++)
    qf[dc] = *(const short8*)&Q[qbase + (size_t)(q0 + fr) * HD + dc * 32 + fg * 8];

  f32x4 acco[8] = {};
  float m_r[4], l_r[4];
#pragma unroll
  for (int r = 0; r < 4; r++) { m_r[r] = -3.0e38f; l_r[r] = 0.f; }

  const int krow = tid >> 4, kslot = tid & 15;
  const int vrow = tid >> 3, vslot = tid & 7;

#pragma unroll 1
  for (int kt = 0; kt < S_SZ; kt += 64) {
#pragma unroll
    for (int i = 0; i < 4; i++) {
      const int row = i * 16 + krow;
      const int c = kslot ^ (row & 7);
      gload16(&Kg[kbase + (size_t)(kt + row) * HD + c * 8], &Ks[i * 2048 + tid * 8]);
    }
#pragma unroll
    for (int i = 0; i < 4; i++) {
      const int row = i * 32 + vrow;
      const int c = vslot ^ (row & 7);
      gload16(&Vt[vbase + (size_t)row * S_SZ + kt + c * 8], &Vs[i * 2048 + tid * 8]);
    }
    __syncthreads();

    f32x4 sf[4] = {};
#pragma unroll
    for (int kb = 0; kb < 4; kb++) {
      const int row = kb * 16 + fr;
#pragma unroll
      for (int dc = 0; dc < 4; dc++) {
        const int slot = (dc * 4 + fg) ^ (row & 7);
        short8 kf = *(const short8*)&Ks[row * 128 + slot * 8];
        sf[kb] = mfma16(qf[dc], kf, sf[kb]);
      }
    }

#pragma unroll
    for (int r = 0; r < 4; r++) {
      float tmax = fmaxf(fmaxf(sf[0][r], sf[1][r]), fmaxf(sf[2][r], sf[3][r]));
      tmax = fmaxf(tmax, __shfl_xor(tmax, 1));
      tmax = fmaxf(tmax, __shfl_xor(tmax, 2));
      tmax = fmaxf(tmax, __shfl_xor(tmax, 4));
      tmax = fmaxf(tmax, __shfl_xor(tmax, 8));
      const float mnew = fmaxf(m_r[r], tmax);
      const float alpha = __builtin_amdgcn_exp2f((m_r[r] - mnew) * CEXP);
      m_r[r] = mnew;
      float ps = 0.f;
      const int prow = fg * 4 + r;
#pragma unroll
      for (int kb = 0; kb < 4; kb++) {
        const unsigned short pb = f2bf(__builtin_amdgcn_exp2f((sf[kb][r] - mnew) * CEXP));
        ps += bf2f(pb);
        Ps[wave][prow * 72 + kb * 16 + fr] = pb;
      }
      ps += __shfl_xor(ps, 1);
      ps += __shfl_xor(ps, 2);
      ps += __shfl_xor(ps, 4);
      ps += __shfl_xor(ps, 8);
      l_r[r] = l_r[r] * alpha + ps;
#pragma unroll
      for (int dt = 0; dt < 8; dt++) acco[dt][r] *= alpha;
    }

    short8 pf[2];
#pragma unroll
    for (int kc = 0; kc < 2; kc++)
      pf[kc] = *(const short8*)&Ps[wave][fr * 72 + kc * 32 + fg * 8];
#pragma unroll
    for (int dt = 0; dt < 8; dt++) {
      const int row = dt * 16 + fr;
#pragma unroll
      for (int kc = 0; kc < 2; kc++) {
        const int slot = (kc * 4 + fg) ^ (row & 7);
        short8 vf = *(const short8*)&Vs[row * 64 + slot * 8];
        acco[dt] = mfma16(pf[kc], vf, acco[dt]);
      }
    }
    __syncthreads();
  }

#pragma unroll
  for (int r = 0; r < 4; r++) {
    const float inv = 1.0f / l_r[r];
    const int s = q0 + fg * 4 + r;
    const size_t ob = (((size_t)(b * S_SZ + s)) * NH + h) * HD;
#pragma unroll
    for (int dt = 0; dt < 8; dt++)
      AO[ob + dt * 16 + fr] = f2bf(acco[dt][r] * inv);
  }
}

// ----------------------------------------------------------------------------
extern "C" void kernel_launch(void* const* d_in, const int* in_sizes, int n_in,
                              void* d_out, int out_size, void* d_ws, size_t ws_size,
                              hipStream_t stream) {
  const float* x  = (const float*)d_in[0];
  const float* wq = (const float*)d_in[1];
  const float* wk = (const float*)d_in[2];
  const float* wv = (const float*)d_in[3];
  const float* wo = (const float*)d_in[4];

  unsigned short* ws = (unsigned short*)d_ws;
  const size_t SZ_BIG = (size_t)DIM_SZ * DIM_SZ;
  const size_t SZ_SMALL = (size_t)(NKV * HD) * DIM_SZ;
  unsigned short* xb   = ws;
  unsigned short* wbig = xb + SZ_BIG;        // wq, later wo
  unsigned short* wkb  = wbig + SZ_BIG;      // wk ++ wv contiguous (N=2048)
  unsigned short* wvb  = wkb + SZ_SMALL;
  unsigned short* Qb   = wvb + SZ_SMALL;     // [b,h,s,d]
  unsigned short* Kb   = Qb + SZ_BIG;        // [b,hk,s,d]
  unsigned short* Vtb  = Kb + SZ_SMALL;      // [b,hk,d,s]
  unsigned short* AOb  = Vtb + SZ_SMALL;     // [b,s,h,d]

  // fp32 -> bf16
  cvt_kernel<<<16384, 256, 0, stream>>>(x, xb, 4194304);
  cvt_kernel<<<16384, 256, 0, stream>>>(wq, wbig, 4194304);
  cvt_kernel<<<4096, 256, 0, stream>>>(wk, wkb, 1048576);
  cvt_kernel<<<4096, 256, 0, stream>>>(wv, wvb, 1048576);

  // Q projection: 256^2 8-phase
  gemm256<1><<<dim3(16, 16), 512, 0, stream>>>(xb, wbig, Qb, 4096, DIM_SZ, NH);
  // K+V merged (N=2048), 128^2, EPI3 routing
  gemm_bt<3><<<dim3(16, 32), 256, 0, stream>>>(xb, wkb, Kb, Vtb, 2048, DIM_SZ, NKV);

  // attention
  attn_kernel<<<dim3(32, 32, 2), 256, 0, stream>>>(Qb, Kb, Vtb, AOb);

  // output projection: 256^2 8-phase, fp32 out
  cvt_kernel<<<16384, 256, 0, stream>>>(wo, wbig, 4194304);
  gemm256<0><<<dim3(16, 16), 512, 0, stream>>>(AOb, wbig, d_out, 4096, DIM_SZ, NH);
}

// Round 3
// 744.186 us; speedup vs baseline: 1.5172x; 1.1685x over previous
//
#include <hip/hip_runtime.h>
#include <stdint.h>

// LlamaGQA on MI355X (gfx950).
// r3: attention rewritten to 8-warp 32x32 swapped-QK^T structure (m214 ladder):
//   - mfma(A=K, B=Q) -> lane owns one q-col, 32 P-values in regs
//   - in-lane softmax (31 fmax + 1 shfl_xor(32)), no LDS P round-trip
//   - P->bf16 B-frags via v_cvt_pk_bf16_f32 + half-swap (shfl_xor+select)
//   - defer-max rescale (skip O-rescale when tile max growth <= 8 exp2-units)
//   - K [64][128] / V^T [128][64] LDS, XOR-swizzled, double-buffered,
//     global_load_lds staged, 1 vmcnt(0)+barrier per tile
// GEMM pipeline unchanged from r2 (gemm256 8-phase Q/O, merged-KV 128^2).

typedef __attribute__((ext_vector_type(4))) float f32x4;
typedef __attribute__((ext_vector_type(16))) float f32x16;
typedef __attribute__((ext_vector_type(4))) float float4v;
typedef __attribute__((ext_vector_type(8))) short short8;
typedef __attribute__((ext_vector_type(8))) __bf16 bf16x8;
typedef __attribute__((ext_vector_type(4))) unsigned short ushort4v;
typedef __attribute__((ext_vector_type(4))) unsigned int uint4v;

#define B_SZ 2
#define S_SZ 2048
#define DIM_SZ 4096
#define NH 32
#define NKV 8
#define HD 128
#define CEXP 0.12752531f  // 1/sqrt(128) * log2(e)

static __device__ __forceinline__ unsigned short f2bf(float f) {
  unsigned int u = __builtin_bit_cast(unsigned int, f);
  u = (u + 0x7fffu + ((u >> 16) & 1u)) >> 16;  // RNE
  return (unsigned short)u;
}
static __device__ __forceinline__ f32x4 mfma16(short8 a, short8 b, f32x4 c) {
  return __builtin_amdgcn_mfma_f32_16x16x32_bf16(
      __builtin_bit_cast(bf16x8, a), __builtin_bit_cast(bf16x8, b), c, 0, 0, 0);
}
static __device__ __forceinline__ f32x16 mfma32(short8 a, short8 b, f32x16 c) {
  return __builtin_amdgcn_mfma_f32_32x32x16_bf16(
      __builtin_bit_cast(bf16x8, a), __builtin_bit_cast(bf16x8, b), c, 0, 0, 0);
}
static __device__ __forceinline__ void gload16(const void* g, void* l) {
  __builtin_amdgcn_global_load_lds(
      (const __attribute__((address_space(1))) unsigned int*)g,
      (__attribute__((address_space(3))) unsigned int*)l, 16, 0, 0);
}
static __device__ __forceinline__ unsigned int cvtpk(float lo, float hi) {
  unsigned int r;
  asm("v_cvt_pk_bf16_f32 %0, %1, %2" : "=v"(r) : "v"(lo), "v"(hi));
  return r;
}

// ---------------- fp32 -> bf16 conversion ----------------------------------
__global__ __launch_bounds__(256) void cvt_kernel(const float* __restrict__ src,
                                                  unsigned short* __restrict__ dst,
                                                  int n4) {
  int i = blockIdx.x * 256 + threadIdx.x;
  if (i >= n4) return;
  float4v v = ((const float4v*)src)[i];
  ushort4v o;
  o[0] = f2bf(v[0]); o[1] = f2bf(v[1]); o[2] = f2bf(v[2]); o[3] = f2bf(v[3]);
  ((ushort4v*)dst)[i] = o;
}

// ---------------- 256x256 8-phase bf16 GEMM (C = A * B^T) -------------------
template <int EPI>
__global__ __launch_bounds__(512, 2) void gemm256(const unsigned short* __restrict__ A,
                                                  const unsigned short* __restrict__ B,
                                                  void* __restrict__ Cout,
                                                  int N, int K, int H) {
  __shared__ unsigned short lds[65536];  // 128 KiB
  const int tid = threadIdx.x;
  const int lane = tid & 63;
  const int wave = tid >> 6;
  const int wm = wave >> 2;
  const int wn = wave & 3;
  const int fr = lane & 15, fg = lane >> 4;
  const int m0 = blockIdx.y * 256, n0 = blockIdx.x * 256;
  const int NT = K >> 6;

  auto seg = [&](int buf, int ab, int half) -> unsigned short* {
    return lds + ((((buf << 1) | ab) << 1) | half) * 8192;
  };

  const int srow = tid >> 3;
  const int scol = ((tid & 7) ^ (srow & 7)) << 3;
  const unsigned short* Abase = A + (size_t)(m0 + srow) * K + scol;
  const unsigned short* Bbase = B + (size_t)(n0 + srow) * K + scol;

  auto stageA = [&](int t, int h) {
    const unsigned short* g = Abase + (size_t)(h * 128) * K + t * 64;
    unsigned short* d = seg(t & 1, 0, h);
    gload16(g, d + tid * 8);
    gload16(g + (size_t)64 * K, d + 4096 + tid * 8);
  };
  auto stageB = [&](int t, int h) {
    const unsigned short* g = Bbase + (size_t)(h * 128) * K + t * 64;
    unsigned short* d = seg(t & 1, 1, h);
    gload16(g, d + tid * 8);
    gload16(g + (size_t)64 * K, d + 4096 + tid * 8);
  };

  f32x4 acc[8][4] = {};

  stageA(0, 0); stageA(0, 1);
  stageB(0, 0); stageB(0, 1);
  stageB(1, 0); stageB(1, 1);
  asm volatile("s_waitcnt vmcnt(4)" ::: "memory");
  __builtin_amdgcn_s_barrier();

#pragma unroll 1
  for (int t = 0; t < NT; ++t) {
    const unsigned short* Aseg = seg(t & 1, 0, wm);
    const unsigned short* Bseg = seg(t & 1, 1, wn >> 1);
    const int brow0 = (wn & 1) * 64;
    short8 aR[4][2], b01[2][2], b23[2][2];

    // phase 1
#pragma unroll
    for (int mi = 0; mi < 4; ++mi)
#pragma unroll
      for (int ks = 0; ks < 2; ++ks) {
        const int row = mi * 16 + fr;
        aR[mi][ks] = *(const short8*)&Aseg[row * 64 + ((((ks << 2) + fg) ^ (row & 7)) << 3)];
      }
#pragma unroll
    for (int ni = 0; ni < 2; ++ni)
#pragma unroll
      for (int ks = 0; ks < 2; ++ks) {
        const int row = brow0 + ni * 16 + fr;
        b01[ni][ks] = *(const short8*)&Bseg[row * 64 + ((((ks << 2) + fg) ^ (row & 7)) << 3)];
      }
    if (t + 1 < NT) stageA(t + 1, 0);
    __builtin_amdgcn_sched_barrier(0);
    __builtin_amdgcn_s_barrier();
    asm volatile("s_waitcnt lgkmcnt(0)" ::: "memory");
    __builtin_amdgcn_sched_barrier(0);
    __builtin_amdgcn_s_setprio(1);
#pragma unroll
    for (int mi = 0; mi < 4; ++mi)
#pragma unroll
      for (int ni = 0; ni < 2; ++ni)
#pragma unroll
        for (int ks = 0; ks < 2; ++ks)
          acc[mi][ni] = mfma16(aR[mi][ks], b01[ni][ks], acc[mi][ni]);
    __builtin_amdgcn_s_setprio(0);
    __builtin_amdgcn_sched_barrier(0);
    __builtin_amdgcn_s_barrier();

    // phase 2
#pragma unroll
    for (int ni = 0; ni < 2; ++ni)
#pragma unroll
      for (int ks = 0; ks < 2; ++ks) {
        const int row = brow0 + (ni + 2) * 16 + fr;
        b23[ni][ks] = *(const short8*)&Bseg[row * 64 + ((((ks << 2) + fg) ^ (row & 7)) << 3)];
      }
    if (t + 1 < NT) stageA(t + 1, 1);
    __builtin_amdgcn_sched_barrier(0);
    __builtin_amdgcn_s_barrier();
    asm volatile("s_waitcnt lgkmcnt(0)" ::: "memory");
    __builtin_amdgcn_sched_barrier(0);
    __builtin_amdgcn_s_setprio(1);
#pragma unroll
    for (int mi = 0; mi < 4; ++mi)
#pragma unroll
      for (int ni = 0; ni < 2; ++ni)
#pragma unroll
        for (int ks = 0; ks < 2; ++ks)
          acc[mi][ni + 2] = mfma16(aR[mi][ks], b23[ni][ks], acc[mi][ni + 2]);
    __builtin_amdgcn_s_setprio(0);
    __builtin_amdgcn_sched_barrier(0);
    __builtin_amdgcn_s_barrier();

    // phase 3
#pragma unroll
    for (int mi = 0; mi < 4; ++mi)
#pragma unroll
      for (int ks = 0; ks < 2; ++ks) {
        const int row = (mi + 4) * 16 + fr;
        aR[mi][ks] = *(const short8*)&Aseg[row * 64 + ((((ks << 2) + fg) ^ (row & 7)) << 3)];
      }
    if (t + 2 < NT) stageB(t + 2, 0);
    __builtin_amdgcn_sched_barrier(0);
    __builtin_amdgcn_s_barrier();
    asm volatile("s_waitcnt lgkmcnt(0)" ::: "memory");
    __builtin_amdgcn_sched_barrier(0);
    __builtin_amdgcn_s_setprio(1);
#pragma unroll
    for (int mi = 0; mi < 4; ++mi)
#pragma unroll
      for (int ni = 0; ni < 2; ++ni)
#pragma unroll
        for (int ks = 0; ks < 2; ++ks)
          acc[mi + 4][ni] = mfma16(aR[mi][ks], b01[ni][ks], acc[mi + 4][ni]);
    __builtin_amdgcn_s_setprio(0);
    __builtin_amdgcn_sched_barrier(0);
    __builtin_amdgcn_s_barrier();

    // phase 4
    if (t + 2 < NT) {
      stageB(t + 2, 1);
      __builtin_amdgcn_sched_barrier(0);
      asm volatile("s_waitcnt vmcnt(4)" ::: "memory");
    } else {
      __builtin_amdgcn_sched_barrier(0);
      asm volatile("s_waitcnt vmcnt(0)" ::: "memory");
    }
    __builtin_amdgcn_s_barrier();
    __builtin_amdgcn_s_setprio(1);
#pragma unroll
    for (int mi = 0; mi < 4; ++mi)
#pragma unroll
      for (int ni = 0; ni < 2; ++ni)
#pragma unroll
        for (int ks = 0; ks < 2; ++ks)
          acc[mi + 4][ni + 2] = mfma16(aR[mi][ks], b23[ni][ks], acc[mi + 4][ni + 2]);
    __builtin_amdgcn_s_setprio(0);
    __builtin_amdgcn_sched_barrier(0);
    __builtin_amdgcn_s_barrier();
  }

#pragma unroll
  for (int mi = 0; mi < 8; ++mi) {
#pragma unroll
    for (int ni = 0; ni < 4; ++ni) {
      const int mb = m0 + wm * 128 + mi * 16 + fg * 4;
      const int n = n0 + wn * 64 + ni * 16 + fr;
      if (EPI == 0) {
        float* C = (float*)Cout;
#pragma unroll
        for (int r = 0; r < 4; ++r) C[(size_t)(mb + r) * N + n] = acc[mi][ni][r];
      } else {
        unsigned short* C = (unsigned short*)Cout;
        const int h = n >> 7, d = n & 127;
#pragma unroll
        for (int r = 0; r < 4; ++r) {
          const int m = mb + r;
          const int bb = m >> 11, s = m & 2047;
          C[(((size_t)(bb * H + h)) * S_SZ + s) * HD + d] = f2bf(acc[mi][ni][r]);
        }
      }
    }
  }
}

// ---------------- 128x128 bf16 GEMM (m97 structure), KV merged --------------
template <int EPI>
__global__ __launch_bounds__(256) void gemm_bt(const unsigned short* __restrict__ A,
                                               const unsigned short* __restrict__ B,
                                               void* __restrict__ Cout,
                                               void* __restrict__ Cout2,
                                               int N, int K, int H) {
  __shared__ unsigned short As[128 * 32];
  __shared__ unsigned short Bs[128 * 32];
  const int tid = threadIdx.x;
  const int lane = tid & 63;
  const int wave = tid >> 6;
  const int wr = wave >> 1, wc = wave & 1;
  const int m0 = blockIdx.y * 128, n0 = blockIdx.x * 128;

  f32x4 acc[4][4] = {};

  const int srow = tid >> 2;
  const int swz8 = ((tid & 3) ^ (srow & 3)) * 8;
  const unsigned short* Ap0 = A + (size_t)(m0 + srow) * K + swz8;
  const unsigned short* Ap1 = Ap0 + (size_t)64 * K;
  const unsigned short* Bp0 = B + (size_t)(n0 + srow) * K + swz8;
  const unsigned short* Bp1 = Bp0 + (size_t)64 * K;
  unsigned short* Ad0 = As + tid * 8;
  unsigned short* Ad1 = As + 2048 + tid * 8;
  unsigned short* Bd0 = Bs + tid * 8;
  unsigned short* Bd1 = Bs + 2048 + tid * 8;

  const int fr = lane & 15;
  const int fg = lane >> 4;
  const int rsl = (fg ^ (fr & 3)) * 8;

#pragma unroll 1
  for (int kt = 0; kt < K; kt += 32) {
    gload16(Ap0 + kt, Ad0);
    gload16(Ap1 + kt, Ad1);
    gload16(Bp0 + kt, Bd0);
    gload16(Bp1 + kt, Bd1);
    __syncthreads();
    short8 a[4], b[4];
#pragma unroll
    for (int i = 0; i < 4; i++)
      a[i] = *(const short8*)&As[(wr * 64 + i * 16 + fr) * 32 + rsl];
#pragma unroll
    for (int i = 0; i < 4; i++)
      b[i] = *(const short8*)&Bs[(wc * 64 + i * 16 + fr) * 32 + rsl];
#pragma unroll
    for (int mi = 0; mi < 4; mi++)
#pragma unroll
      for (int ni = 0; ni < 4; ni++)
        acc[mi][ni] = mfma16(a[mi], b[ni], acc[mi][ni]);
    __syncthreads();
  }

#pragma unroll
  for (int mi = 0; mi < 4; mi++) {
#pragma unroll
    for (int ni = 0; ni < 4; ni++) {
      const int mb = m0 + wr * 64 + mi * 16 + fg * 4;
      const int n = n0 + wc * 64 + ni * 16 + fr;
      if (EPI == 0) {
        float* C = (float*)Cout;
#pragma unroll
        for (int r = 0; r < 4; r++) C[(size_t)(mb + r) * N + n] = acc[mi][ni][r];
      } else if (EPI == 3) {
        if (n < 1024) {  // K: [b,hk,s,d]
          unsigned short* C = (unsigned short*)Cout;
          const int h = n >> 7, d = n & 127;
#pragma unroll
          for (int r = 0; r < 4; r++) {
            const int m = mb + r;
            const int bb = m >> 11, s = m & 2047;
            C[(((size_t)(bb * NKV + h)) * S_SZ + s) * HD + d] = f2bf(acc[mi][ni][r]);
          }
        } else {  // V^T: [b,hk,d,s]
          unsigned short* C = (unsigned short*)Cout2;
          const int vr = n - 1024;
          const int h = vr >> 7, d = vr & 127;
          const int bb = mb >> 11, s = mb & 2047;
          ushort4v pk;
#pragma unroll
          for (int r = 0; r < 4; r++) pk[r] = f2bf(acc[mi][ni][r]);
          *(ushort4v*)&C[(((size_t)(bb * NKV + h)) * HD + d) * S_SZ + s] = pk;
        }
      }
    }
  }
}

// ---------------- flash attention: 8-warp 32x32 swapped-QK^T ----------------
// Block: 512 thr = 8 warps, each owns 32 q-rows of one (b,h). KVBLK=64.
// Swapped S: mfma(A=K,B=Q) -> D[key][q], lane col = q (lane&31), 16 regs x
// 2 key-blocks = 32 P-values/lane. Softmax in-lane; P->B-frags via cvt_pk +
// half-swap. PV: mfma(A=V^T, B=P) -> O[d][q], col=q: acco 4x f32x16.
__global__ __launch_bounds__(512) void attn_kernel(const unsigned short* __restrict__ Q,
                                                   const unsigned short* __restrict__ Kg,
                                                   const unsigned short* __restrict__ Vt,
                                                   unsigned short* __restrict__ AO) {
  __shared__ unsigned short Ks[2][64 * 128];
  __shared__ unsigned short Vs[2][128 * 64];
  const int tid = threadIdx.x, lane = tid & 63, w = tid >> 6;
  const int l31 = lane & 31, h = lane >> 5;
  const int qt = blockIdx.x, hq = blockIdx.y, b = blockIdx.z;
  const int hk = hq >> 2;  // groups = 4
  const size_t qbase = ((size_t)(b * NH + hq) * S_SZ) * HD;
  const size_t kbase = ((size_t)(b * NKV + hk) * S_SZ) * HD;
  const size_t vbase = ((size_t)(b * NKV + hk) * HD) * S_SZ;
  const int q = qt * 256 + w * 32 + l31;

  // Q B-frags: row=q (lane&31), k-chunk c*16 + h*8
  short8 qf[8];
#pragma unroll
  for (int c = 0; c < 8; ++c)
    qf[c] = *(const short8*)&Q[qbase + (size_t)q * HD + c * 16 + h * 8];

  // staging: 2 chunks (16B) per thread per tensor per tile
  const int p0 = tid, p1 = tid + 512;
  const int kr0 = p0 >> 4, kc0 = ((p0 & 15) ^ (kr0 & 7)) << 3;
  const int kr1 = p1 >> 4, kc1 = ((p1 & 15) ^ (kr1 & 7)) << 3;
  const int vr0 = p0 >> 3, vc0 = ((p0 & 7) ^ (vr0 & 7)) << 3;
  const int vr1 = p1 >> 3, vc1 = ((p1 & 7) ^ (vr1 & 7)) << 3;

  auto stage = [&](int bufi, int kt) {
    gload16(&Kg[kbase + (size_t)(kt + kr0) * HD + kc0], &Ks[bufi][p0 * 8]);
    gload16(&Kg[kbase + (size_t)(kt + kr1) * HD + kc1], &Ks[bufi][p1 * 8]);
    gload16(&Vt[vbase + (size_t)vr0 * S_SZ + kt + vc0], &Vs[bufi][p0 * 8]);
    gload16(&Vt[vbase + (size_t)vr1 * S_SZ + kt + vc1], &Vs[bufi][p1 * 8]);
  };

  f32x16 ao[4] = {};
  float m_r = -3.0e38f, l_r = 0.f;

  stage(0, 0);
  asm volatile("s_waitcnt vmcnt(0)" ::: "memory");
  __syncthreads();

#pragma unroll 1
  for (int t = 0; t < 32; ++t) {
    const int cur = t & 1;
    if (t + 1 < 32) stage(cur ^ 1, (t + 1) * 64);
    const unsigned short* K_ = Ks[cur];
    const unsigned short* V_ = Vs[cur];

    // S^T = K Q^T : sf[kb][reg] = S[key = kb*32 + row(reg,h)][q = l31]
    f32x16 sf[2] = {};
#pragma unroll
    for (int kb = 0; kb < 2; ++kb) {
      const int row = kb * 32 + l31;
#pragma unroll
      for (int c = 0; c < 8; ++c) {
        const int ch = (c * 2 + h) ^ (row & 7);
        short8 kf = *(const short8*)&K_[row * 128 + ch * 8];
        sf[kb] = mfma32(kf, qf[c], sf[kb]);
      }
    }

    // tile max (in-lane 31 fmax + half-swap)
    float tm = sf[0][0];
#pragma unroll
    for (int r = 1; r < 16; ++r) tm = fmaxf(tm, sf[0][r]);
#pragma unroll
    for (int r = 0; r < 16; ++r) tm = fmaxf(tm, sf[1][r]);
    tm = fmaxf(tm, __shfl_xor(tm, 32));

    // defer-max: rescale only when max grew by > 8 exp2-units
    const bool skip = ((tm - m_r) * CEXP <= 8.0f);
    if (!__all(skip)) {
      const float mnew = fmaxf(m_r, tm);
      const float al = __builtin_amdgcn_exp2f((m_r - mnew) * CEXP);
      l_r *= al;
#pragma unroll
      for (int db = 0; db < 4; ++db)
#pragma unroll
        for (int r = 0; r < 16; ++r) ao[db][r] *= al;
      m_r = mnew;
    }

    // P = exp2(S*CEXP - m*CEXP), row-sum
    const float nmc = -m_r * CEXP;
    float p[2][16];
    float ps = 0.f;
#pragma unroll
    for (int kb = 0; kb < 2; ++kb)
#pragma unroll
      for (int r = 0; r < 16; ++r) {
        p[kb][r] = __builtin_amdgcn_exp2f(fmaf(sf[kb][r], CEXP, nmc));
        ps += p[kb][r];
      }
    ps += __shfl_xor(ps, 32);
    l_r += ps;

    // pack P into 4 B-frags (keys f*16..f*16+15), words via cvt_pk + half-swap
    uint4v pw[4];
#pragma unroll
    for (int kb = 0; kb < 2; ++kb)
#pragma unroll
      for (int hs = 0; hs < 2; ++hs) {
        const int f = kb * 2 + hs;
        const unsigned int X  = cvtpk(p[kb][hs * 8 + 0], p[kb][hs * 8 + 1]);
        const unsigned int X2 = cvtpk(p[kb][hs * 8 + 2], p[kb][hs * 8 + 3]);
        const unsigned int Y  = cvtpk(p[kb][hs * 8 + 4], p[kb][hs * 8 + 5]);
        const unsigned int Y2 = cvtpk(p[kb][hs * 8 + 6], p[kb][hs * 8 + 7]);
        const unsigned int xs  = __shfl_xor(X, 32);
        const unsigned int xs2 = __shfl_xor(X2, 32);
        const unsigned int ys  = __shfl_xor(Y, 32);
        const unsigned int ys2 = __shfl_xor(Y2, 32);
        pw[f][0] = h ? ys : X;    // keys 8h+0, 8h+1
        pw[f][1] = h ? ys2 : X2;  // keys 8h+2, 8h+3
        pw[f][2] = h ? Y : xs;    // keys 8h+4, 8h+5
        pw[f][3] = h ? Y2 : xs2;  // keys 8h+6, 8h+7
      }

    // O += P V : mfma(A=V^T frag, B=P frag) -> D[d][q]
#pragma unroll
    for (int db = 0; db < 4; ++db) {
      const int row = db * 32 + l31;
#pragma unroll
      for (int f = 0; f < 4; ++f) {
        const int ch = (f * 2 + h) ^ (row & 7);
        short8 vf = *(const short8*)&V_[row * 64 + ch * 8];
        ao[db] = mfma32(vf, __builtin_bit_cast(short8, pw[f]), ao[db]);
      }
    }

    asm volatile("s_waitcnt vmcnt(0)" ::: "memory");
    __syncthreads();
  }

  // epilogue: AO[b][s=q][hq][d], d = db*32 + rg*8 + 4h + j
  const float inv = 1.0f / l_r;
  const size_t ob = (((size_t)(b * S_SZ + q)) * NH + hq) * HD;
#pragma unroll
  for (int db = 0; db < 4; ++db)
#pragma unroll
    for (int rg = 0; rg < 4; ++rg) {
      const int d0 = db * 32 + rg * 8 + h * 4;
      ushort4v pk;
#pragma unroll
      for (int j = 0; j < 4; ++j) pk[j] = f2bf(ao[db][rg * 4 + j] * inv);
      *(ushort4v*)&AO[ob + d0] = pk;
    }
}

// ----------------------------------------------------------------------------
extern "C" void kernel_launch(void* const* d_in, const int* in_sizes, int n_in,
                              void* d_out, int out_size, void* d_ws, size_t ws_size,
                              hipStream_t stream) {
  const float* x  = (const float*)d_in[0];
  const float* wq = (const float*)d_in[1];
  const float* wk = (const float*)d_in[2];
  const float* wv = (const float*)d_in[3];
  const float* wo = (const float*)d_in[4];

  unsigned short* ws = (unsigned short*)d_ws;
  const size_t SZ_BIG = (size_t)DIM_SZ * DIM_SZ;
  const size_t SZ_SMALL = (size_t)(NKV * HD) * DIM_SZ;
  unsigned short* xb   = ws;
  unsigned short* wbig = xb + SZ_BIG;        // wq, later wo
  unsigned short* wkb  = wbig + SZ_BIG;      // wk ++ wv contiguous (N=2048)
  unsigned short* wvb  = wkb + SZ_SMALL;
  unsigned short* Qb   = wvb + SZ_SMALL;     // [b,h,s,d]
  unsigned short* Kb   = Qb + SZ_BIG;        // [b,hk,s,d]
  unsigned short* Vtb  = Kb + SZ_SMALL;      // [b,hk,d,s]
  unsigned short* AOb  = Vtb + SZ_SMALL;     // [b,s,h,d]

  cvt_kernel<<<16384, 256, 0, stream>>>(x, xb, 4194304);
  cvt_kernel<<<16384, 256, 0, stream>>>(wq, wbig, 4194304);
  cvt_kernel<<<4096, 256, 0, stream>>>(wk, wkb, 1048576);
  cvt_kernel<<<4096, 256, 0, stream>>>(wv, wvb, 1048576);

  gemm256<1><<<dim3(16, 16), 512, 0, stream>>>(xb, wbig, Qb, 4096, DIM_SZ, NH);
  gemm_bt<3><<<dim3(16, 32), 256, 0, stream>>>(xb, wkb, Kb, Vtb, 2048, DIM_SZ, NKV);

  attn_kernel<<<dim3(8, 32, 2), 512, 0, stream>>>(Qb, Kb, Vtb, AOb);

  cvt_kernel<<<16384, 256, 0, stream>>>(wo, wbig, 4194304);
  gemm256<0><<<dim3(16, 16), 512, 0, stream>>>(AOb, wbig, d_out, 4096, DIM_SZ, NH);
}

// Round 6
// 720.057 us; speedup vs baseline: 1.5680x; 1.0335x over previous
//
#include <hip/hip_runtime.h>
#include <stdint.h>

// LlamaGQA on MI355X (gfx950).
// r5 (resubmit; r5 bench was GPUAcquisitionTimeout — no data):
//     fix r4's halfswap register-coalescing hazard: inline-asm
//     v_permlane32_swap_b32 with two identical "+v" operands could be
//     allocated to ONE register (self-swap garbage) -> broken running max.
//     Replaced with __builtin_amdgcn_permlane32_swap (SSA, T12 recipe).
//     XCD swizzle on gemm256/gemm_bt kept from r4 (re-verified bijective).

typedef __attribute__((ext_vector_type(4))) float f32x4;
typedef __attribute__((ext_vector_type(16))) float f32x16;
typedef __attribute__((ext_vector_type(4))) float float4v;
typedef __attribute__((ext_vector_type(8))) short short8;
typedef __attribute__((ext_vector_type(8))) __bf16 bf16x8;
typedef __attribute__((ext_vector_type(4))) unsigned short ushort4v;
typedef __attribute__((ext_vector_type(4))) unsigned int uint4v;
typedef __attribute__((ext_vector_type(2))) unsigned int uint2v;

#define B_SZ 2
#define S_SZ 2048
#define DIM_SZ 4096
#define NH 32
#define NKV 8
#define HD 128
#define CEXP 0.12752531f  // 1/sqrt(128) * log2(e)

static __device__ __forceinline__ unsigned short f2bf(float f) {
  unsigned int u = __builtin_bit_cast(unsigned int, f);
  u = (u + 0x7fffu + ((u >> 16) & 1u)) >> 16;  // RNE
  return (unsigned short)u;
}
static __device__ __forceinline__ f32x4 mfma16(short8 a, short8 b, f32x4 c) {
  return __builtin_amdgcn_mfma_f32_16x16x32_bf16(
      __builtin_bit_cast(bf16x8, a), __builtin_bit_cast(bf16x8, b), c, 0, 0, 0);
}
static __device__ __forceinline__ f32x16 mfma32(short8 a, short8 b, f32x16 c) {
  return __builtin_amdgcn_mfma_f32_32x32x16_bf16(
      __builtin_bit_cast(bf16x8, a), __builtin_bit_cast(bf16x8, b), c, 0, 0, 0);
}
static __device__ __forceinline__ void gload16(const void* g, void* l) {
  __builtin_amdgcn_global_load_lds(
      (const __attribute__((address_space(1))) unsigned int*)g,
      (__attribute__((address_space(3))) unsigned int*)l, 16, 0, 0);
}
static __device__ __forceinline__ unsigned int cvtpk(float lo, float hi) {
  unsigned int r;
  asm("v_cvt_pk_bf16_f32 %0, %1, %2" : "=v"(r) : "v"(lo), "v"(hi));
  return r;
}
// permlane32_swap(a,b): ret[0] = [a.lanes0-31 ; b.lanes0-31->32-63],
//                       ret[1] = [a.lanes32-63->0-31 ; b.lanes32-63]
static __device__ __forceinline__ uint2v plswap(unsigned int a, unsigned int b) {
  return __builtin_amdgcn_permlane32_swap(a, b, false, false);
}
// value of x from the other 32-lane half (h = lane>>5)
static __device__ __forceinline__ float halfswap(float x, int h) {
  const unsigned int u = __builtin_bit_cast(unsigned int, x);
  uint2v r = plswap(u, u);
  return __builtin_bit_cast(float, h ? r[0] : r[1]);
}

// ---------------- fp32 -> bf16 conversion ----------------------------------
__global__ __launch_bounds__(256) void cvt_kernel(const float* __restrict__ src,
                                                  unsigned short* __restrict__ dst,
                                                  int n4) {
  int i = blockIdx.x * 256 + threadIdx.x;
  if (i >= n4) return;
  float4v v = ((const float4v*)src)[i];
  ushort4v o;
  o[0] = f2bf(v[0]); o[1] = f2bf(v[1]); o[2] = f2bf(v[2]); o[3] = f2bf(v[3]);
  ((ushort4v*)dst)[i] = o;
}

// ---------------- 256x256 8-phase bf16 GEMM (C = A * B^T) -------------------
template <int EPI>
__global__ __launch_bounds__(512, 2) void gemm256(const unsigned short* __restrict__ A,
                                                  const unsigned short* __restrict__ B,
                                                  void* __restrict__ Cout,
                                                  int N, int K, int H) {
  __shared__ unsigned short lds[65536];  // 128 KiB
  const int tid = threadIdx.x;
  const int lane = tid & 63;
  const int wave = tid >> 6;
  const int wm = wave >> 2;
  const int wn = wave & 3;
  const int fr = lane & 15, fg = lane >> 4;
  // XCD-aware bijective swizzle (nwg % 8 == 0 for our grids)
  const int nwg = gridDim.x * gridDim.y;
  int lin = blockIdx.y * gridDim.x + blockIdx.x;
  lin = (lin & 7) * (nwg >> 3) + (lin >> 3);
  const int m0 = (lin / gridDim.x) * 256, n0 = (lin % gridDim.x) * 256;
  const int NT = K >> 6;

  auto seg = [&](int buf, int ab, int half) -> unsigned short* {
    return lds + ((((buf << 1) | ab) << 1) | half) * 8192;
  };

  const int srow = tid >> 3;
  const int scol = ((tid & 7) ^ (srow & 7)) << 3;
  const unsigned short* Abase = A + (size_t)(m0 + srow) * K + scol;
  const unsigned short* Bbase = B + (size_t)(n0 + srow) * K + scol;

  auto stageA = [&](int t, int h) {
    const unsigned short* g = Abase + (size_t)(h * 128) * K + t * 64;
    unsigned short* d = seg(t & 1, 0, h);
    gload16(g, d + tid * 8);
    gload16(g + (size_t)64 * K, d + 4096 + tid * 8);
  };
  auto stageB = [&](int t, int h) {
    const unsigned short* g = Bbase + (size_t)(h * 128) * K + t * 64;
    unsigned short* d = seg(t & 1, 1, h);
    gload16(g, d + tid * 8);
    gload16(g + (size_t)64 * K, d + 4096 + tid * 8);
  };

  f32x4 acc[8][4] = {};

  stageA(0, 0); stageA(0, 1);
  stageB(0, 0); stageB(0, 1);
  stageB(1, 0); stageB(1, 1);
  asm volatile("s_waitcnt vmcnt(4)" ::: "memory");
  __builtin_amdgcn_s_barrier();

#pragma unroll 1
  for (int t = 0; t < NT; ++t) {
    const unsigned short* Aseg = seg(t & 1, 0, wm);
    const unsigned short* Bseg = seg(t & 1, 1, wn >> 1);
    const int brow0 = (wn & 1) * 64;
    short8 aR[4][2], b01[2][2], b23[2][2];

    // phase 1
#pragma unroll
    for (int mi = 0; mi < 4; ++mi)
#pragma unroll
      for (int ks = 0; ks < 2; ++ks) {
        const int row = mi * 16 + fr;
        aR[mi][ks] = *(const short8*)&Aseg[row * 64 + ((((ks << 2) + fg) ^ (row & 7)) << 3)];
      }
#pragma unroll
    for (int ni = 0; ni < 2; ++ni)
#pragma unroll
      for (int ks = 0; ks < 2; ++ks) {
        const int row = brow0 + ni * 16 + fr;
        b01[ni][ks] = *(const short8*)&Bseg[row * 64 + ((((ks << 2) + fg) ^ (row & 7)) << 3)];
      }
    if (t + 1 < NT) stageA(t + 1, 0);
    __builtin_amdgcn_sched_barrier(0);
    __builtin_amdgcn_s_barrier();
    asm volatile("s_waitcnt lgkmcnt(0)" ::: "memory");
    __builtin_amdgcn_sched_barrier(0);
    __builtin_amdgcn_s_setprio(1);
#pragma unroll
    for (int mi = 0; mi < 4; ++mi)
#pragma unroll
      for (int ni = 0; ni < 2; ++ni)
#pragma unroll
        for (int ks = 0; ks < 2; ++ks)
          acc[mi][ni] = mfma16(aR[mi][ks], b01[ni][ks], acc[mi][ni]);
    __builtin_amdgcn_s_setprio(0);
    __builtin_amdgcn_sched_barrier(0);
    __builtin_amdgcn_s_barrier();

    // phase 2
#pragma unroll
    for (int ni = 0; ni < 2; ++ni)
#pragma unroll
      for (int ks = 0; ks < 2; ++ks) {
        const int row = brow0 + (ni + 2) * 16 + fr;
        b23[ni][ks] = *(const short8*)&Bseg[row * 64 + ((((ks << 2) + fg) ^ (row & 7)) << 3)];
      }
    if (t + 1 < NT) stageA(t + 1, 1);
    __builtin_amdgcn_sched_barrier(0);
    __builtin_amdgcn_s_barrier();
    asm volatile("s_waitcnt lgkmcnt(0)" ::: "memory");
    __builtin_amdgcn_sched_barrier(0);
    __builtin_amdgcn_s_setprio(1);
#pragma unroll
    for (int mi = 0; mi < 4; ++mi)
#pragma unroll
      for (int ni = 0; ni < 2; ++ni)
#pragma unroll
        for (int ks = 0; ks < 2; ++ks)
          acc[mi][ni + 2] = mfma16(aR[mi][ks], b23[ni][ks], acc[mi][ni + 2]);
    __builtin_amdgcn_s_setprio(0);
    __builtin_amdgcn_sched_barrier(0);
    __builtin_amdgcn_s_barrier();

    // phase 3
#pragma unroll
    for (int mi = 0; mi < 4; ++mi)
#pragma unroll
      for (int ks = 0; ks < 2; ++ks) {
        const int row = (mi + 4) * 16 + fr;
        aR[mi][ks] = *(const short8*)&Aseg[row * 64 + ((((ks << 2) + fg) ^ (row & 7)) << 3)];
      }
    if (t + 2 < NT) stageB(t + 2, 0);
    __builtin_amdgcn_sched_barrier(0);
    __builtin_amdgcn_s_barrier();
    asm volatile("s_waitcnt lgkmcnt(0)" ::: "memory");
    __builtin_amdgcn_sched_barrier(0);
    __builtin_amdgcn_s_setprio(1);
#pragma unroll
    for (int mi = 0; mi < 4; ++mi)
#pragma unroll
      for (int ni = 0; ni < 2; ++ni)
#pragma unroll
        for (int ks = 0; ks < 2; ++ks)
          acc[mi + 4][ni] = mfma16(aR[mi][ks], b01[ni][ks], acc[mi + 4][ni]);
    __builtin_amdgcn_s_setprio(0);
    __builtin_amdgcn_sched_barrier(0);
    __builtin_amdgcn_s_barrier();

    // phase 4
    if (t + 2 < NT) {
      stageB(t + 2, 1);
      __builtin_amdgcn_sched_barrier(0);
      asm volatile("s_waitcnt vmcnt(4)" ::: "memory");
    } else {
      __builtin_amdgcn_sched_barrier(0);
      asm volatile("s_waitcnt vmcnt(0)" ::: "memory");
    }
    __builtin_amdgcn_s_barrier();
    __builtin_amdgcn_s_setprio(1);
#pragma unroll
    for (int mi = 0; mi < 4; ++mi)
#pragma unroll
      for (int ni = 0; ni < 2; ++ni)
#pragma unroll
        for (int ks = 0; ks < 2; ++ks)
          acc[mi + 4][ni + 2] = mfma16(aR[mi][ks], b23[ni][ks], acc[mi + 4][ni + 2]);
    __builtin_amdgcn_s_setprio(0);
    __builtin_amdgcn_sched_barrier(0);
    __builtin_amdgcn_s_barrier();
  }

#pragma unroll
  for (int mi = 0; mi < 8; ++mi) {
#pragma unroll
    for (int ni = 0; ni < 4; ++ni) {
      const int mb = m0 + wm * 128 + mi * 16 + fg * 4;
      const int n = n0 + wn * 64 + ni * 16 + fr;
      if (EPI == 0) {
        float* C = (float*)Cout;
#pragma unroll
        for (int r = 0; r < 4; ++r) C[(size_t)(mb + r) * N + n] = acc[mi][ni][r];
      } else {
        unsigned short* C = (unsigned short*)Cout;
        const int h = n >> 7, d = n & 127;
#pragma unroll
        for (int r = 0; r < 4; ++r) {
          const int m = mb + r;
          const int bb = m >> 11, s = m & 2047;
          C[(((size_t)(bb * H + h)) * S_SZ + s) * HD + d] = f2bf(acc[mi][ni][r]);
        }
      }
    }
  }
}

// ---------------- 128x128 bf16 GEMM (m97 structure), KV merged --------------
template <int EPI>
__global__ __launch_bounds__(256) void gemm_bt(const unsigned short* __restrict__ A,
                                               const unsigned short* __restrict__ B,
                                               void* __restrict__ Cout,
                                               void* __restrict__ Cout2,
                                               int N, int K, int H) {
  __shared__ unsigned short As[128 * 32];
  __shared__ unsigned short Bs[128 * 32];
  const int tid = threadIdx.x;
  const int lane = tid & 63;
  const int wave = tid >> 6;
  const int wr = wave >> 1, wc = wave & 1;
  // XCD-aware bijective swizzle (nwg % 8 == 0)
  const int nwg = gridDim.x * gridDim.y;
  int lin = blockIdx.y * gridDim.x + blockIdx.x;
  lin = (lin & 7) * (nwg >> 3) + (lin >> 3);
  const int m0 = (lin / gridDim.x) * 128, n0 = (lin % gridDim.x) * 128;

  f32x4 acc[4][4] = {};

  const int srow = tid >> 2;
  const int swz8 = ((tid & 3) ^ (srow & 3)) * 8;
  const unsigned short* Ap0 = A + (size_t)(m0 + srow) * K + swz8;
  const unsigned short* Ap1 = Ap0 + (size_t)64 * K;
  const unsigned short* Bp0 = B + (size_t)(n0 + srow) * K + swz8;
  const unsigned short* Bp1 = Bp0 + (size_t)64 * K;
  unsigned short* Ad0 = As + tid * 8;
  unsigned short* Ad1 = As + 2048 + tid * 8;
  unsigned short* Bd0 = Bs + tid * 8;
  unsigned short* Bd1 = Bs + 2048 + tid * 8;

  const int fr = lane & 15;
  const int fg = lane >> 4;
  const int rsl = (fg ^ (fr & 3)) * 8;

#pragma unroll 1
  for (int kt = 0; kt < K; kt += 32) {
    gload16(Ap0 + kt, Ad0);
    gload16(Ap1 + kt, Ad1);
    gload16(Bp0 + kt, Bd0);
    gload16(Bp1 + kt, Bd1);
    __syncthreads();
    short8 a[4], b[4];
#pragma unroll
    for (int i = 0; i < 4; i++)
      a[i] = *(const short8*)&As[(wr * 64 + i * 16 + fr) * 32 + rsl];
#pragma unroll
    for (int i = 0; i < 4; i++)
      b[i] = *(const short8*)&Bs[(wc * 64 + i * 16 + fr) * 32 + rsl];
#pragma unroll
    for (int mi = 0; mi < 4; mi++)
#pragma unroll
      for (int ni = 0; ni < 4; ni++)
        acc[mi][ni] = mfma16(a[mi], b[ni], acc[mi][ni]);
    __syncthreads();
  }

#pragma unroll
  for (int mi = 0; mi < 4; mi++) {
#pragma unroll
    for (int ni = 0; ni < 4; ni++) {
      const int mb = m0 + wr * 64 + mi * 16 + fg * 4;
      const int n = n0 + wc * 64 + ni * 16 + fr;
      if (EPI == 0) {
        float* C = (float*)Cout;
#pragma unroll
        for (int r = 0; r < 4; r++) C[(size_t)(mb + r) * N + n] = acc[mi][ni][r];
      } else if (EPI == 3) {
        if (n < 1024) {  // K: [b,hk,s,d]
          unsigned short* C = (unsigned short*)Cout;
          const int h = n >> 7, d = n & 127;
#pragma unroll
          for (int r = 0; r < 4; r++) {
            const int m = mb + r;
            const int bb = m >> 11, s = m & 2047;
            C[(((size_t)(bb * NKV + h)) * S_SZ + s) * HD + d] = f2bf(acc[mi][ni][r]);
          }
        } else {  // V^T: [b,hk,d,s]
          unsigned short* C = (unsigned short*)Cout2;
          const int vr = n - 1024;
          const int h = vr >> 7, d = vr & 127;
          const int bb = mb >> 11, s = mb & 2047;
          ushort4v pk;
#pragma unroll
          for (int r = 0; r < 4; r++) pk[r] = f2bf(acc[mi][ni][r]);
          *(ushort4v*)&C[(((size_t)(bb * NKV + h)) * HD + d) * S_SZ + s] = pk;
        }
      }
    }
  }
}

// ---------------- flash attention: 8-warp 32x32 swapped-QK^T ----------------
__global__ __launch_bounds__(512) void attn_kernel(const unsigned short* __restrict__ Q,
                                                   const unsigned short* __restrict__ Kg,
                                                   const unsigned short* __restrict__ Vt,
                                                   unsigned short* __restrict__ AO) {
  __shared__ unsigned short Ks[2][64 * 128];
  __shared__ unsigned short Vs[2][128 * 64];
  const int tid = threadIdx.x, lane = tid & 63, w = tid >> 6;
  const int l31 = lane & 31, h = lane >> 5;
  const int qt = blockIdx.x, hq = blockIdx.y, b = blockIdx.z;
  const int hk = hq >> 2;  // groups = 4
  const size_t qbase = ((size_t)(b * NH + hq) * S_SZ) * HD;
  const size_t kbase = ((size_t)(b * NKV + hk) * S_SZ) * HD;
  const size_t vbase = ((size_t)(b * NKV + hk) * HD) * S_SZ;
  const int q = qt * 256 + w * 32 + l31;

  short8 qf[8];
#pragma unroll
  for (int c = 0; c < 8; ++c)
    qf[c] = *(const short8*)&Q[qbase + (size_t)q * HD + c * 16 + h * 8];

  const int p0 = tid, p1 = tid + 512;
  const int kr0 = p0 >> 4, kc0 = ((p0 & 15) ^ (kr0 & 7)) << 3;
  const int kr1 = p1 >> 4, kc1 = ((p1 & 15) ^ (kr1 & 7)) << 3;
  const int vr0 = p0 >> 3, vc0 = ((p0 & 7) ^ (vr0 & 7)) << 3;
  const int vr1 = p1 >> 3, vc1 = ((p1 & 7) ^ (vr1 & 7)) << 3;

  auto stage = [&](int bufi, int kt) {
    gload16(&Kg[kbase + (size_t)(kt + kr0) * HD + kc0], &Ks[bufi][p0 * 8]);
    gload16(&Kg[kbase + (size_t)(kt + kr1) * HD + kc1], &Ks[bufi][p1 * 8]);
    gload16(&Vt[vbase + (size_t)vr0 * S_SZ + kt + vc0], &Vs[bufi][p0 * 8]);
    gload16(&Vt[vbase + (size_t)vr1 * S_SZ + kt + vc1], &Vs[bufi][p1 * 8]);
  };

  f32x16 ao[4] = {};
  float m_r = -3.0e38f, l_r = 0.f;

  stage(0, 0);
  asm volatile("s_waitcnt vmcnt(0)" ::: "memory");
  __syncthreads();

#pragma unroll 1
  for (int t = 0; t < 32; ++t) {
    const int cur = t & 1;
    if (t + 1 < 32) stage(cur ^ 1, (t + 1) * 64);
    const unsigned short* K_ = Ks[cur];
    const unsigned short* V_ = Vs[cur];

    // S^T = K Q^T
    f32x16 sf[2] = {};
#pragma unroll
    for (int kb = 0; kb < 2; ++kb) {
      const int row = kb * 32 + l31;
#pragma unroll
      for (int c = 0; c < 8; ++c) {
        const int ch = (c * 2 + h) ^ (row & 7);
        short8 kf = *(const short8*)&K_[row * 128 + ch * 8];
        sf[kb] = mfma32(kf, qf[c], sf[kb]);
      }
    }

    // tile max (in-lane 31 fmax + permlane half-swap)
    float tm = sf[0][0];
#pragma unroll
    for (int r = 1; r < 16; ++r) tm = fmaxf(tm, sf[0][r]);
#pragma unroll
    for (int r = 0; r < 16; ++r) tm = fmaxf(tm, sf[1][r]);
    tm = fmaxf(tm, halfswap(tm, h));

    // defer-max: rescale only when max grew by > 8 exp2-units
    const bool skip = ((tm - m_r) * CEXP <= 8.0f);
    if (!__all(skip)) {
      const float mnew = fmaxf(m_r, tm);
      const float al = __builtin_amdgcn_exp2f((m_r - mnew) * CEXP);
      l_r *= al;
#pragma unroll
      for (int db = 0; db < 4; ++db)
#pragma unroll
        for (int r = 0; r < 16; ++r) ao[db][r] *= al;
      m_r = mnew;
    }

    // P = exp2(S*CEXP - m*CEXP), row-sum
    const float nmc = -m_r * CEXP;
    float p[2][16];
    float ps = 0.f;
#pragma unroll
    for (int kb = 0; kb < 2; ++kb)
#pragma unroll
      for (int r = 0; r < 16; ++r) {
        p[kb][r] = __builtin_amdgcn_exp2f(fmaf(sf[kb][r], CEXP, nmc));
        ps += p[kb][r];
      }
    ps += halfswap(ps, h);
    l_r += ps;

    // pack P into 4 B-frags; one permlane32_swap fills two words
    uint4v pw[4];
#pragma unroll
    for (int kb = 0; kb < 2; ++kb)
#pragma unroll
      for (int hs = 0; hs < 2; ++hs) {
        const int f = kb * 2 + hs;
        const unsigned int X1 = cvtpk(p[kb][hs * 8 + 0], p[kb][hs * 8 + 1]);
        const unsigned int Y1 = cvtpk(p[kb][hs * 8 + 4], p[kb][hs * 8 + 5]);
        const unsigned int X2 = cvtpk(p[kb][hs * 8 + 2], p[kb][hs * 8 + 3]);
        const unsigned int Y2 = cvtpk(p[kb][hs * 8 + 6], p[kb][hs * 8 + 7]);
        uint2v s1 = plswap(X1, Y1);  // [0]->word0, [1]->word2
        uint2v s2 = plswap(X2, Y2);  // [0]->word1, [1]->word3
        pw[f][0] = s1[0]; pw[f][1] = s2[0]; pw[f][2] = s1[1]; pw[f][3] = s2[1];
      }

    // O += P V
#pragma unroll
    for (int db = 0; db < 4; ++db) {
      const int row = db * 32 + l31;
#pragma unroll
      for (int f = 0; f < 4; ++f) {
        const int ch = (f * 2 + h) ^ (row & 7);
        short8 vf = *(const short8*)&V_[row * 64 + ch * 8];
        ao[db] = mfma32(vf, __builtin_bit_cast(short8, pw[f]), ao[db]);
      }
    }

    asm volatile("s_waitcnt vmcnt(0)" ::: "memory");
    __syncthreads();
  }

  // epilogue: AO[b][s=q][hq][d]
  const float inv = 1.0f / l_r;
  const size_t ob = (((size_t)(b * S_SZ + q)) * NH + hq) * HD;
#pragma unroll
  for (int db = 0; db < 4; ++db)
#pragma unroll
    for (int rg = 0; rg < 4; ++rg) {
      const int d0 = db * 32 + rg * 8 + h * 4;
      ushort4v pk;
#pragma unroll
      for (int j = 0; j < 4; ++j) pk[j] = f2bf(ao[db][rg * 4 + j] * inv);
      *(ushort4v*)&AO[ob + d0] = pk;
    }
}

// ----------------------------------------------------------------------------
extern "C" void kernel_launch(void* const* d_in, const int* in_sizes, int n_in,
                              void* d_out, int out_size, void* d_ws, size_t ws_size,
                              hipStream_t stream) {
  const float* x  = (const float*)d_in[0];
  const float* wq = (const float*)d_in[1];
  const float* wk = (const float*)d_in[2];
  const float* wv = (const float*)d_in[3];
  const float* wo = (const float*)d_in[4];

  unsigned short* ws = (unsigned short*)d_ws;
  const size_t SZ_BIG = (size_t)DIM_SZ * DIM_SZ;
  const size_t SZ_SMALL = (size_t)(NKV * HD) * DIM_SZ;
  unsigned short* xb   = ws;
  unsigned short* wbig = xb + SZ_BIG;        // wq, later wo
  unsigned short* wkb  = wbig + SZ_BIG;      // wk ++ wv contiguous (N=2048)
  unsigned short* wvb  = wkb + SZ_SMALL;
  unsigned short* Qb   = wvb + SZ_SMALL;     // [b,h,s,d]
  unsigned short* Kb   = Qb + SZ_BIG;        // [b,hk,s,d]
  unsigned short* Vtb  = Kb + SZ_SMALL;      // [b,hk,d,s]
  unsigned short* AOb  = Vtb + SZ_SMALL;     // [b,s,h,d]

  cvt_kernel<<<16384, 256, 0, stream>>>(x, xb, 4194304);
  cvt_kernel<<<16384, 256, 0, stream>>>(wq, wbig, 4194304);
  cvt_kernel<<<4096, 256, 0, stream>>>(wk, wkb, 1048576);
  cvt_kernel<<<4096, 256, 0, stream>>>(wv, wvb, 1048576);

  gemm256<1><<<dim3(16, 16), 512, 0, stream>>>(xb, wbig, Qb, 4096, DIM_SZ, NH);
  gemm_bt<3><<<dim3(16, 32), 256, 0, stream>>>(xb, wkb, Kb, Vtb, 2048, DIM_SZ, NKV);

  attn_kernel<<<dim3(8, 32, 2), 512, 0, stream>>>(Qb, Kb, Vtb, AOb);

  cvt_kernel<<<16384, 256, 0, stream>>>(wo, wbig, 4194304);
  gemm256<0><<<dim3(16, 16), 512, 0, stream>>>(AOb, wbig, d_out, 4096, DIM_SZ, NH);
}